// Round 7
// baseline (19.804 us; speedup 1.0000x reference)
//
#include <hip/hip_runtime.h>

#define NCAND 40
#define NC2   1600
#define NP    256

// ---------------- Kernel 1: candidate patch distances (float32, numpy-exact) ----
// Wave-per-candidate. Lane = c*16 + h*8 + u (lanes 0..47 active, 48..63 compute
// harmless duplicates). Each lane runs one 16-step sequential accumulator chain
// r[u]; the numpy pairwise tree ((r0+r1)+(r2+r3))+((r4+r5)+(r6+r7)) is realized
// bit-exactly by a shfl_xor butterfly (IEEE add commutes), xor8 merges halves,
// explicit shfl from lanes 16/32 gives the sequential channel sum (p0+p1)+p2.
// All ops via __f*_rn intrinsics to block fp-contract=fast.
// DO NOT change the arithmetic order here: patch_ids correctness depends on
// bit-exact replication of the numpy f32 reduction tree.
__global__ void k_dist(const float* __restrict__ feat0,
                       const int* __restrict__ loc,
                       float* __restrict__ dist) {
    __shared__ float smp[3 * 16 * 16];
    const int lh = loc[0], lw = loc[1];
    for (int t = threadIdx.x; t < 768; t += 256) {
        int c = t >> 8;
        int rem = t & 255;
        int a = rem >> 4;
        int b = rem & 15;
        smp[t] = feat0[c * 65536 + (lh - 8 + a) * 256 + (lw - 8 + b)];
    }
    __syncthreads();

    const int wid  = threadIdx.x >> 6;
    const int lane = threadIdx.x & 63;
    const int cand = blockIdx.x * 4 + wid;          // 400 blocks * 4 waves = 1600
    const int i = cand / NCAND;
    const int j = cand % NCAND;
    const int base_h = lh - 28 + i;
    const int base_w = lw - 28 + j;

    int c = lane >> 4;
    if (c > 2) c = 0;                               // lanes 48..63: duplicate c=0
    const int h = (lane >> 3) & 1;
    const int u = lane & 7;
    const float* fp = feat0 + c * 65536;
    const float* sc = smp + c * 256;

    float r = 0.0f;
#pragma unroll
    for (int k = 0; k < 16; ++k) {
        const int idx = h * 128 + k * 8 + u;        // flat a*16+b within the patch
        const int a = idx >> 4;
        const int b = idx & 15;
        float v = fp[(base_h + a) * 256 + base_w + b];
        float d = __fsub_rn(v, sc[idx]);
        float sq = __fmul_rn(d, d);
        r = (k == 0) ? sq : __fadd_rn(r, sq);
    }
    // pairwise tree over u (bit-exact butterfly), then halves (h bit)
    r = __fadd_rn(r, __shfl_xor(r, 1, 64));
    r = __fadd_rn(r, __shfl_xor(r, 2, 64));
    r = __fadd_rn(r, __shfl_xor(r, 4, 64));
    r = __fadd_rn(r, __shfl_xor(r, 8, 64));
    // sequential channel combine (p0+p1)+p2, valid on lane 0
    float p1 = __shfl(r, 16, 64);
    float p2 = __shfl(r, 32, 64);
    float tot = __fadd_rn(__fadd_rn(r, p1), p2);
    if (lane == 0) dist[cand] = __fsqrt_rn(tot);
}

// ---- per-wave gather + L2-normalize for one (feature, rank-row) ------------
// C known at compile time: loops fully unroll, x[] stays in registers.
// Scattered loads are independent (pipeline); stores are lane-consecutive.
template <int C, int H>
__device__ __forceinline__ void wave_gather(const float* __restrict__ src,
                                            long off, int r, int h, int w,
                                            int lane, float* __restrict__ out) {
    const int hh = (h * H) / 256;                   // == patch_ids * H // IMG_RES
    const int ww = (w * H) / 256;
    const long HW = (long)H * H;
    const long base = (long)hh * H + ww;

    float x[(C + 63) / 64];
    float acc = 0.f;
#pragma unroll
    for (int m = 0; m < (C + 63) / 64; ++m) {
        const int c = lane + m * 64;
        float v = (c < C) ? src[(long)c * HW + base] : 0.f;
        x[m] = v;
        acc = fmaf(v, v, acc);
    }
    acc += __shfl_xor(acc, 1, 64);
    acc += __shfl_xor(acc, 2, 64);
    acc += __shfl_xor(acc, 4, 64);
    acc += __shfl_xor(acc, 8, 64);
    acc += __shfl_xor(acc, 16, 64);
    acc += __shfl_xor(acc, 32, 64);
    const float scale = 1.0f / (sqrtf(acc) + 1e-7f);
#pragma unroll
    for (int m = 0; m < (C + 63) / 64; ++m) {
        const int c = lane + m * 64;
        if (c < C) out[off + (long)r * C + c] = x[m] * scale;
    }
}

// ---------------- Kernel 2: rank selection + fused gather -------------------
// Wave t computes rank(t) = #{k : d[k]<d[t] || (d[k]==d[t] && k<t)} (strict
// total order == top_k tie-break; predicate identical to the verified R4/R6
// kernel). A wave whose candidate ranks in the top-256 then directly performs
// the gather+normalize for output row `rank` across all four features --
// no hw[] round-trip, no third dispatch.
__global__ void k_rankgather(const float* __restrict__ dist,
                             const int* __restrict__ loc,
                             const float* __restrict__ feat0,
                             const float* __restrict__ feat1,
                             const float* __restrict__ feat2,
                             const float* __restrict__ feat3,
                             float* __restrict__ out) {
    __shared__ float ds[NC2];
    for (int k = threadIdx.x; k < NC2; k += 256) ds[k] = dist[k];
    __syncthreads();

    const int wid  = threadIdx.x >> 6;
    const int lane = threadIdx.x & 63;
    const int t = blockIdx.x * 4 + wid;             // 400 blocks * 4 waves = 1600
    const float dt = ds[t];
    int rank = 0;
#pragma unroll
    for (int m = 0; m < NC2 / 64; ++m) {
        const int k = lane + (m << 6);
        const float dk = ds[k];
        rank += (dk < dt || (dk == dt && k < t)) ? 1 : 0;
    }
    rank += __shfl_xor(rank, 1, 64);
    rank += __shfl_xor(rank, 2, 64);
    rank += __shfl_xor(rank, 4, 64);
    rank += __shfl_xor(rank, 8, 64);
    rank += __shfl_xor(rank, 16, 64);
    rank += __shfl_xor(rank, 32, 64);
    // rank is identical across the wave -> the branch below is wave-uniform.

    if (rank < NP) {
        const int lh = loc[0], lw = loc[1];
        const int h = lh - 20 + t / NCAND;
        const int w = lw - 20 + t % NCAND;
        if (lane == 0) {
            float* out_ids = out + 768 + 65536 + 131072 + 262144;
            out_ids[rank * 2]     = (float)h;
            out_ids[rank * 2 + 1] = (float)w;
        }
        wave_gather<3,    256>(feat0, 0,                      rank, h, w, lane, out);
        wave_gather<256,  256>(feat1, 768,                    rank, h, w, lane, out);
        wave_gather<512,  128>(feat2, 768 + 65536,            rank, h, w, lane, out);
        wave_gather<1024, 64 >(feat3, 768 + 65536 + 131072,   rank, h, w, lane, out);
    }
}

extern "C" void kernel_launch(void* const* d_in, const int* in_sizes, int n_in,
                              void* d_out, int out_size, void* d_ws, size_t ws_size,
                              hipStream_t stream) {
    const float* feat0 = (const float*)d_in[0];
    const float* feat1 = (const float*)d_in[1];
    const float* feat2 = (const float*)d_in[2];
    const float* feat3 = (const float*)d_in[3];
    const int*   loc   = (const int*)d_in[4];
    float* out = (float*)d_out;

    float* dist = (float*)d_ws;                              // 1600 floats

    k_dist<<<NC2 / 4, 256, 0, stream>>>(feat0, loc, dist);
    k_rankgather<<<NC2 / 4, 256, 0, stream>>>(dist, loc, feat0, feat1, feat2, feat3, out);
}

// Round 8
// 18.342 us; speedup vs baseline: 1.0797x; 1.0797x over previous
//
#include <hip/hip_runtime.h>

#define NCAND 40
#define NC2   1600
#define NP    256

// ---------------- Kernel 1: candidate patch distances (float32, numpy-exact) ----
// Barrier-free wave-per-candidate. Lane = c*16 + h*8 + u (lanes 48..63 compute
// harmless duplicates of c=0). Sample values are loaded directly from global
// (identical bits to the former LDS staging -> arithmetic is bit-identical to
// the verified kernel): numpy pairwise tree ((r0+r1)+(r2+r3))+((r4+r5)+(r6+r7))
// via shfl_xor butterfly, halves via xor8, channels sequential (p0+p1)+p2.
// All ops via __f*_rn intrinsics to block fp-contract=fast.
// DO NOT change the arithmetic order: patch_ids correctness depends on it.
__global__ void k_dist(const float* __restrict__ feat0,
                       const int* __restrict__ loc,
                       float* __restrict__ dist) {
    const int wid  = threadIdx.x >> 6;
    const int lane = threadIdx.x & 63;
    const int lh = loc[0], lw = loc[1];
    const int cand = blockIdx.x * 4 + wid;          // 400 blocks * 4 waves = 1600
    const int i = cand / NCAND;
    const int j = cand % NCAND;
    const int base_h = lh - 28 + i;
    const int base_w = lw - 28 + j;

    int c = lane >> 4;
    if (c > 2) c = 0;                               // lanes 48..63: duplicate c=0
    const int h = (lane >> 3) & 1;
    const int u = lane & 7;
    const float* fp = feat0 + c * 65536;

    // preload all 32 values (16 window + 16 sample) -- independent loads,
    // single latency exposure; the serial part is only the 16-add chain.
    float v[16], s[16];
#pragma unroll
    for (int k = 0; k < 16; ++k) {
        const int idx = h * 128 + k * 8 + u;        // flat a*16+b within the patch
        const int a = idx >> 4;
        const int b = idx & 15;
        v[k] = fp[(base_h + a) * 256 + base_w + b];
        s[k] = fp[(lh - 8 + a) * 256 + (lw - 8 + b)];
    }
    float r = 0.0f;
#pragma unroll
    for (int k = 0; k < 16; ++k) {
        float d = __fsub_rn(v[k], s[k]);
        float sq = __fmul_rn(d, d);
        r = (k == 0) ? sq : __fadd_rn(r, sq);
    }
    // pairwise tree over u (bit-exact butterfly), then halves (h bit)
    r = __fadd_rn(r, __shfl_xor(r, 1, 64));
    r = __fadd_rn(r, __shfl_xor(r, 2, 64));
    r = __fadd_rn(r, __shfl_xor(r, 4, 64));
    r = __fadd_rn(r, __shfl_xor(r, 8, 64));
    // sequential channel combine (p0+p1)+p2, valid on lane 0
    float p1 = __shfl(r, 16, 64);
    float p2 = __shfl(r, 32, 64);
    float tot = __fadd_rn(__fadd_rn(r, p1), p2);
    if (lane == 0) dist[cand] = __fsqrt_rn(tot);
}

// ---- speculative per-wave gather: load x[] for this wave's own (h,w) -------
template <int C, int H>
__device__ __forceinline__ void gather_load(const float* __restrict__ src,
                                            int h, int w, int lane,
                                            float* __restrict__ x) {
    const int hh = (h * H) / 256;                   // == patch_ids * H // IMG_RES
    const int ww = (w * H) / 256;
    const long HW = (long)H * H;
    const long base = (long)hh * H + ww;
#pragma unroll
    for (int m = 0; m < (C + 63) / 64; ++m) {
        const int c = lane + m * 64;
        x[m] = (c < C) ? src[(long)c * HW + base] : 0.f;
    }
}

template <int C>
__device__ __forceinline__ void gather_store(const float* __restrict__ x,
                                             long off, int r, int lane,
                                             float* __restrict__ out) {
    float acc = 0.f;
#pragma unroll
    for (int m = 0; m < (C + 63) / 64; ++m) acc = fmaf(x[m], x[m], acc);
    acc += __shfl_xor(acc, 1, 64);
    acc += __shfl_xor(acc, 2, 64);
    acc += __shfl_xor(acc, 4, 64);
    acc += __shfl_xor(acc, 8, 64);
    acc += __shfl_xor(acc, 16, 64);
    acc += __shfl_xor(acc, 32, 64);
    const float scale = 1.0f / (sqrtf(acc) + 1e-7f);
#pragma unroll
    for (int m = 0; m < (C + 63) / 64; ++m) {
        const int c = lane + m * 64;
        if (c < C) out[off + (long)r * C + c] = x[m] * scale;
    }
}

// ---------------- Kernel 2: rank + fused speculative gather -----------------
// Barrier/LDS-free. Wave t: lane reads dist[lane+64m] (m<25, coalesced, L2)
// into registers; rank(t) = #{k : d[k]<d[t] || (d[k]==d[t] && k<t)} -- the
// exact predicate of the verified kernel. Gather DATA depends only on (h,w)
// (the wave's own candidate), not on rank, so all 29 scattered loads are
// issued speculatively up front and fly under the rank scan; only the
// reduce+store is conditional on rank<256.
__global__ void k_rankgather(const float* __restrict__ dist,
                             const int* __restrict__ loc,
                             const float* __restrict__ feat0,
                             const float* __restrict__ feat1,
                             const float* __restrict__ feat2,
                             const float* __restrict__ feat3,
                             float* __restrict__ out) {
    const int wid  = threadIdx.x >> 6;
    const int lane = threadIdx.x & 63;
    const int t = blockIdx.x * 4 + wid;             // 400 blocks * 4 waves = 1600
    const int lh = loc[0], lw = loc[1];
    const int h = lh - 20 + t / NCAND;
    const int w = lw - 20 + t % NCAND;

    // issue the scan loads first (needed first)...
    const float dt = dist[t];                       // wave-uniform broadcast
    float dk[NC2 / 64];
#pragma unroll
    for (int m = 0; m < NC2 / 64; ++m) dk[m] = dist[lane + (m << 6)];

    // ...then the speculative gather loads (waited on only after the scan)
    float x0[1], x1[4], x2[8], x3[16];
    gather_load<3,    256>(feat0, h, w, lane, x0);
    gather_load<256,  256>(feat1, h, w, lane, x1);
    gather_load<512,  128>(feat2, h, w, lane, x2);
    gather_load<1024, 64 >(feat3, h, w, lane, x3);

    int rank = 0;
#pragma unroll
    for (int m = 0; m < NC2 / 64; ++m) {
        const int k = lane + (m << 6);
        rank += (dk[m] < dt || (dk[m] == dt && k < t)) ? 1 : 0;
    }
    rank += __shfl_xor(rank, 1, 64);
    rank += __shfl_xor(rank, 2, 64);
    rank += __shfl_xor(rank, 4, 64);
    rank += __shfl_xor(rank, 8, 64);
    rank += __shfl_xor(rank, 16, 64);
    rank += __shfl_xor(rank, 32, 64);
    // rank is identical across the wave -> wave-uniform branch.

    if (rank < NP) {
        if (lane == 0) {
            float* out_ids = out + 768 + 65536 + 131072 + 262144;
            out_ids[rank * 2]     = (float)h;
            out_ids[rank * 2 + 1] = (float)w;
        }
        gather_store<3   >(x0, 0,                       rank, lane, out);
        gather_store<256 >(x1, 768,                     rank, lane, out);
        gather_store<512 >(x2, 768 + 65536,             rank, lane, out);
        gather_store<1024>(x3, 768 + 65536 + 131072,    rank, lane, out);
    }
}

extern "C" void kernel_launch(void* const* d_in, const int* in_sizes, int n_in,
                              void* d_out, int out_size, void* d_ws, size_t ws_size,
                              hipStream_t stream) {
    const float* feat0 = (const float*)d_in[0];
    const float* feat1 = (const float*)d_in[1];
    const float* feat2 = (const float*)d_in[2];
    const float* feat3 = (const float*)d_in[3];
    const int*   loc   = (const int*)d_in[4];
    float* out = (float*)d_out;

    float* dist = (float*)d_ws;                              // 1600 floats

    k_dist<<<NC2 / 4, 256, 0, stream>>>(feat0, loc, dist);
    k_rankgather<<<NC2 / 4, 256, 0, stream>>>(dist, loc, feat0, feat1, feat2, feat3, out);
}